// Round 1
// baseline (333.851 us; speedup 1.0000x reference)
//
#include <hip/hip_runtime.h>

#define N_NODES 50000
#define N_GRAPHS 128
#define HID 512

// Split-K geometry: Psum[128 x 512] = C[128 x K] * x[K x 512]
// KS2=48 -> grid 16x48 = 768 blocks = 8 XCD x 32 CU x 3 blocks/CU (fully
// co-resident), enabling the XCD-locality remap in pool_gemm5.
#define KSPAN   272                      // 17 k-steps of 16 per wave
#define NSTEP   17
#define KS2     48                       // part slices (one per k-group)
#define KSPLIT  (KS2 * 4)                // 192 wave-level k-splits
#define KPAD    (KSPAN * KSPLIT)         // 52224
#define NPANEL  (KPAD / 16)              // 3264

// Workspace layout (16B-aligned sections)
#define C8_OFF     0
#define C8_BYTES   ((size_t)N_GRAPHS * KPAD)                 // 6,684,672
#define PSUM_OFF   (C8_OFF + C8_BYTES)
#define PSUM_BYTES ((size_t)N_GRAPHS * HID * 4)              // 262,144
#define COUNTS_OFF (PSUM_OFF + PSUM_BYTES)
#define ZERO_BYTES (COUNTS_OFF + 512)                        // zero C8+Psum+counts
#define APACK_OFF  ZERO_BYTES
#define APACK_BYTES ((size_t)NPANEL * 4 * 64 * 16)           // 13,369,344
#define PART_OFF   (APACK_OFF + APACK_BYTES)
#define PART_BYTES ((size_t)KS2 * N_GRAPHS * HID * 4)        // 12,582,912
#define WAUG_OFF   (PART_OFF + PART_BYTES)
#define WAUG_BYTES ((size_t)3 * 513 * HID * 4)               // 3,151,872

typedef __attribute__((ext_vector_type(8))) short bf16x8;
typedef __attribute__((ext_vector_type(16))) float f32x16;

// ---------------------------------------------------------------------------
// Build byte-packed counts C8[g][node] (row stride KPAD) + per-graph path
// counts via LDS histogram.
// ---------------------------------------------------------------------------
__global__ __launch_bounds__(256)
void build_c_kernel(const int* __restrict__ w2, const int* __restrict__ w3,
                    const int* __restrict__ w4, const int* __restrict__ batch,
                    unsigned int* __restrict__ C32, int* __restrict__ counts) {
    __shared__ int hist[N_GRAPHS];
    const int t = threadIdx.x;
    if (t < N_GRAPHS) hist[t] = 0;
    __syncthreads();
    const int i = blockIdx.x * 256 + t;
    if (i < N_NODES) {
        const int a = w2[i];            // walk2[0][i] — path anchor
        const int g = batch[a];
        atomicAdd(&hist[g], 1);
        unsigned int* row = C32 + (size_t)g * (KPAD / 4);
        int nn[12];
        nn[0]  = a;
        nn[1]  = w2[N_NODES + i];
        nn[2]  = w2[2 * N_NODES + i];
        nn[3]  = w3[i];
        nn[4]  = w3[N_NODES + i];
        nn[5]  = w3[2 * N_NODES + i];
        nn[6]  = w3[3 * N_NODES + i];
        nn[7]  = w4[i];
        nn[8]  = w4[N_NODES + i];
        nn[9]  = w4[2 * N_NODES + i];
        nn[10] = w4[3 * N_NODES + i];
        nn[11] = w4[4 * N_NODES + i];
#pragma unroll
        for (int j = 0; j < 12; ++j) {
            const int nd = nn[j];
            atomicAdd(&row[nd >> 2], 1u << ((nd & 3) * 8));
        }
    }
    __syncthreads();
    if (t < N_GRAPHS) { const int hv = hist[t]; if (hv) atomicAdd(&counts[t], hv); }
}

__device__ inline unsigned pack_bf16(unsigned a, unsigned b) {
    // exact: u8 -> f32 -> truncate to bf16 (u8 mantissa fits in bf16)
    return (__builtin_bit_cast(unsigned, (float)a) >> 16) |
           (__builtin_bit_cast(unsigned, (float)b) & 0xFFFF0000u);
}

// ---------------------------------------------------------------------------
// Repack u8 counts into MFMA A-fragment order:
// Apack[(kp*4 + mt)*64 + lane] = 8 bf16 of row (mt*32 + lane&31),
// k = kp*16 + 8*(lane>>5) + 0..7.
// ---------------------------------------------------------------------------
__global__ __launch_bounds__(256)
void c8_to_apack_kernel(const unsigned char* __restrict__ C8,
                        uint4* __restrict__ Apack) {
    const int kp = blockIdx.x;           // 0..NPANEL-1
    const int t = threadIdx.x;
    const int mt = t >> 6;
    const int l = t & 63;
    const int row = mt * 32 + (l & 31);
    const int k0 = kp * 16 + 8 * (l >> 5);
    const uint2 b = *(const uint2*)(C8 + (size_t)row * KPAD + k0);
    uint4 o;
    o.x = pack_bf16(b.x & 0xFFu, (b.x >> 8) & 0xFFu);
    o.y = pack_bf16((b.x >> 16) & 0xFFu, b.x >> 24);
    o.z = pack_bf16(b.y & 0xFFu, (b.y >> 8) & 0xFFu);
    o.w = pack_bf16((b.y >> 16) & 0xFFu, b.y >> 24);
    Apack[(size_t)(kp * 4 + mt) * 64 + l] = o;
}

// ---------------------------------------------------------------------------
// B-load: 16 global dwords per step per lane, straight into VGPRs in the
// exact MFMA B-fragment layout (k = 8h+j, n = lane&31; two 32-col groups).
// Each wave-instr covers 2 full 128B lines. GUARD clamps k for the tail
// split (A is zero there, so clamped values contribute nothing).
// ---------------------------------------------------------------------------
template <int GUARD>
__device__ inline void issue_b(const float* __restrict__ xp, int krow,
                               unsigned (&u)[16]) {
#pragma unroll
    for (int j = 0; j < 8; ++j) {
        int k = krow + j;
        if (GUARD) k = min(k, N_NODES - 1);
        const float* p = xp + (size_t)k * HID;
        u[j]     = __builtin_bit_cast(unsigned, p[0]);
        u[8 + j] = __builtin_bit_cast(unsigned, p[32]);
    }
}

__device__ inline f32x16 mfma_bf16(bf16x8 a, bf16x8 b, f32x16 c) {
    return __builtin_amdgcn_mfma_f32_32x32x16_bf16(a, b, c, 0, 0, 0);
}

// one v_perm per dword: [b0,b1]=u0.bytes[2,3], [b2,b3]=u1.bytes[2,3]
__device__ inline unsigned bpack(unsigned u0, unsigned u1) {
    return __builtin_amdgcn_perm(u1, u0, 0x07060302u);
}

__device__ inline void step_mfma(const unsigned (&u)[16], const uint4 (&a)[2],
                                 f32x16 (&acc)[2][2]) {
    unsigned d0[4], d1[4];
#pragma unroll
    for (int jj = 0; jj < 4; ++jj) {
        d0[jj] = bpack(u[2 * jj], u[2 * jj + 1]);
        d1[jj] = bpack(u[8 + 2 * jj], u[8 + 2 * jj + 1]);
    }
    const bf16x8 b0 = __builtin_bit_cast(bf16x8, make_uint4(d0[0], d0[1], d0[2], d0[3]));
    const bf16x8 b1 = __builtin_bit_cast(bf16x8, make_uint4(d1[0], d1[1], d1[2], d1[3]));
    const bf16x8 a0 = __builtin_bit_cast(bf16x8, a[0]);
    const bf16x8 a1 = __builtin_bit_cast(bf16x8, a[1]);
    acc[0][0] = mfma_bf16(a0, b0, acc[0][0]);
    acc[0][1] = mfma_bf16(a0, b1, acc[0][1]);
    acc[1][0] = mfma_bf16(a1, b0, acc[1][0]);
    acc[1][1] = mfma_bf16(a1, b1, acc[1][1]);
}

// 3-deep register software pipeline over NSTEP k-steps: every wave keeps
// ~51 loads (12 KB) in flight continuously — no barriers, no LDS staging.
template <int GUARD>
__device__ inline void run_k(const float* __restrict__ xp,
                             const uint4* __restrict__ Apack,
                             int kbase, int h, int lane, int rm,
                             f32x16 (&acc)[2][2]) {
    unsigned bu[3][16];
    uint4 au[3][2];
    const int kp0 = kbase >> 4;
#pragma unroll
    for (int s = 0; s < 3; ++s) {
        issue_b<GUARD>(xp, kbase + s * 16 + 8 * h, bu[s]);
        au[s][0] = Apack[(size_t)((kp0 + s) * 4 + rm * 2) * 64 + lane];
        au[s][1] = Apack[(size_t)((kp0 + s) * 4 + rm * 2 + 1) * 64 + lane];
    }
#pragma unroll
    for (int s = 0; s < NSTEP; ++s) {
        const int slot = s % 3;
        step_mfma(bu[slot], au[slot], acc);
        if (s + 3 < NSTEP) {
            issue_b<GUARD>(xp, kbase + (s + 3) * 16 + 8 * h, bu[slot]);
            au[slot][0] = Apack[(size_t)((kp0 + s + 3) * 4 + rm * 2) * 64 + lane];
            au[slot][1] = Apack[(size_t)((kp0 + s + 3) * 4 + rm * 2 + 1) * 64 + lane];
        }
    }
}

// ---------------------------------------------------------------------------
// Barrier-free-K split-K MFMA GEMM. grid=(16, KS2), block=256.
// XCD-locality remap: linear block id l -> xcd=l&7 (HW round-robin), and we
// assign ALL 16 region-blocks of one k-group to one XCD, dispatch-adjacent.
// The rm-pair sharing each 64-col x slice and the 8 rn-blocks sharing each
// Apack slice then hit the same L2 -> x and Apack are fetched from HBM once.
// ---------------------------------------------------------------------------
template <int ATOMIC>
__global__ __launch_bounds__(256, 3)
void pool_gemm5_kernel(const float* __restrict__ x,
                       const uint4* __restrict__ Apack,
                       float* __restrict__ dst) {
    __shared__ float red[3][2][64 * 16];     // 24 KB
    const int t = threadIdx.x;
    const int lane = t & 63;
    const int w = t >> 6;
    const int n = lane & 31;
    const int h = lane >> 5;

    const int lb = blockIdx.x + 16 * blockIdx.y;   // 0..767
    const int xcd = lb & 7;
    const int j = lb >> 3;                          // 0..95
    const int region = j & 15;                      // 16 regions of this ksg
    const int ksg = xcd * (KS2 / 8) + (j >> 4);     // 0..47, 6 k-groups/XCD
    const int rm = region & 1;
    const int rn = region >> 1;
    const int ks = ksg * 4 + w;
    const int kbase = ks * KSPAN;

    f32x16 acc[2][2];
#pragma unroll
    for (int p = 0; p < 2; ++p)
#pragma unroll
        for (int q = 0; q < 2; ++q)
#pragma unroll
            for (int r = 0; r < 16; ++r) acc[p][q][r] = 0.f;

    const float* xp = x + rn * 64 + n;       // column base for this lane

    if (kbase + KSPAN <= N_NODES) {
        run_k<0>(xp, Apack, kbase, h, lane, rm, acc);
    } else if (kbase < N_NODES) {
        run_k<1>(xp, Apack, kbase, h, lane, rm, acc);
    }
    // fully-OOB waves: acc stays 0, still join the barriers below

    float* outp = ATOMIC ? dst : dst + (size_t)ksg * (N_GRAPHS * HID);
#pragma unroll
    for (int p = 0; p < 2; ++p) {
        __syncthreads();
        if (w > 0) {
#pragma unroll
            for (int q = 0; q < 2; ++q)
#pragma unroll
                for (int i = 0; i < 16; ++i)
                    red[w - 1][q][i * 64 + lane] = acc[p][q][i];
        }
        __syncthreads();
        if (w == 0) {
#pragma unroll
            for (int q = 0; q < 2; ++q)
#pragma unroll
                for (int i = 0; i < 16; ++i) {
                    const float v = acc[p][q][i] + red[0][q][i * 64 + lane] +
                                    red[1][q][i * 64 + lane] + red[2][q][i * 64 + lane];
                    // C/D layout: col=lane&31, row=(i&3)+8*(i>>2)+4*h
                    const int row = rm * 64 + p * 32 + (i & 3) + 8 * (i >> 2) + 4 * h;
                    const int col = rn * 64 + q * 32 + n;
                    if (ATOMIC) atomicAdd(&outp[(size_t)row * HID + col], v);
                    else        outp[(size_t)row * HID + col] = v;
                }
        }
    }
}

// ---------------------------------------------------------------------------
// Psum = sum over KS2 partials (coalesced streams)
// ---------------------------------------------------------------------------
__global__ __launch_bounds__(256)
void reduce_part_kernel(const float* __restrict__ part, float* __restrict__ Psum) {
    const int id = blockIdx.x * 256 + threadIdx.x;
    float s0 = 0.f, s1 = 0.f;
    for (int k = 0; k + 2 <= KS2; k += 2) {
        s0 += part[(size_t)k * (N_GRAPHS * HID) + id];
        s1 += part[(size_t)(k + 1) * (N_GRAPHS * HID) + id];
    }
    Psum[id] = s0 + s1;
}

// ---------------------------------------------------------------------------
// Weight-chain collapse: pooling is linear, so
//   g_l = Pn @ Weff_l + mask * beff_l,   Weff_l = W0*...*Wl,
//   beff_0 = 12*b0,  beff_l = beff_{l-1} @ Wl + 12*bl.
// Waug_l is [513][512]: rows 0..511 = Weff_l, row 512 = beff_l.
// ---------------------------------------------------------------------------
__global__ __launch_bounds__(256)
void waug_init_kernel(const float* __restrict__ W0, const float* __restrict__ b0,
                      float* __restrict__ Aout) {
    const int id = blockIdx.x * 256 + threadIdx.x;
    if (id < 512 * 512)      Aout[id] = W0[id];
    else if (id < 513 * 512) Aout[id] = 12.f * b0[id - 512 * 512];
}

// Aout[513x512] = Ain[513x512] @ W[512x512]  (+ 12*b on the bias row)
__global__ __launch_bounds__(256)
void wchain_kernel(const float* __restrict__ Ain, const float* __restrict__ W,
                   const float* __restrict__ b, float* __restrict__ Aout) {
    __shared__ float Alds[16][512];          // 32 KB
    const int t = threadIdx.x;
    const int ct = blockIdx.x;               // 0..7  (64-col tiles)
    const int rt = blockIdx.y;               // 0..32 (16-row tiles over 513)
    const int cc = ct * 64 + (t & 63);
    for (int idx = t; idx < 16 * 128; idx += 256) {
        const int rr = idx >> 7;
        const int kk = (idx & 127) * 4;
        const int row = rt * 16 + rr;
        float4 v = (row < 513) ? *(const float4*)&Ain[(size_t)row * 512 + kk]
                               : make_float4(0.f, 0.f, 0.f, 0.f);
        *(float4*)&Alds[rr][kk] = v;
    }
    __syncthreads();
    const int wv = t >> 6;
    float a0 = 0.f, a1 = 0.f, a2 = 0.f, a3 = 0.f;
#pragma unroll 8
    for (int k = 0; k < 512; ++k) {
        const float wval = W[(size_t)k * 512 + cc];
        a0 += Alds[wv * 4 + 0][k] * wval;
        a1 += Alds[wv * 4 + 1][k] * wval;
        a2 += Alds[wv * 4 + 2][k] * wval;
        a3 += Alds[wv * 4 + 3][k] * wval;
    }
    const int r0 = rt * 16 + wv * 4;
    float acc[4] = {a0, a1, a2, a3};
#pragma unroll
    for (int i = 0; i < 4; ++i) {
        const int row = r0 + i;
        if (row < 513)
            Aout[(size_t)row * 512 + cc] = acc[i] + (row == 512 ? 12.f * b[cc] : 0.f);
    }
}

// ---------------------------------------------------------------------------
// One fused epilogue GEMM: out[128 x 1536], layer l = ct>>3, direct stores
// (no atomics, no output zeroing). A = Psum/counts staged once per row-tile.
// ---------------------------------------------------------------------------
__global__ __launch_bounds__(256)
void fused_layers_kernel(const float* __restrict__ Psum,
                         const float* __restrict__ Waug,   // [3][513][512]
                         const int* __restrict__ counts,
                         float* __restrict__ out) {
    __shared__ float Alds[16][512];          // 32 KB
    const int t = threadIdx.x;
    const int ct = blockIdx.x;               // 0..23  (3 layers x 8 col-tiles)
    const int rt = blockIdx.y;               // 0..7
    const int l = ct >> 3;
    const int ccl = (ct & 7) * 64 + (t & 63);
    for (int idx = t; idx < 16 * 128; idx += 256) {
        const int rr = idx >> 7;
        const int kk = (idx & 127) * 4;
        const int row = rt * 16 + rr;
        float4 v = *(const float4*)&Psum[(size_t)row * 512 + kk];
        const float inv = 1.f / (float)max(counts[row], 1);
        v.x *= inv; v.y *= inv; v.z *= inv; v.w *= inv;
        *(float4*)&Alds[rr][kk] = v;
    }
    __syncthreads();
    const float* W = Waug + (size_t)l * (513 * 512);
    const int wv = t >> 6;
    float a0 = 0.f, a1 = 0.f, a2 = 0.f, a3 = 0.f;
#pragma unroll 8
    for (int k = 0; k < 512; ++k) {
        const float wval = W[(size_t)k * 512 + ccl];
        a0 += Alds[wv * 4 + 0][k] * wval;
        a1 += Alds[wv * 4 + 1][k] * wval;
        a2 += Alds[wv * 4 + 2][k] * wval;
        a3 += Alds[wv * 4 + 3][k] * wval;
    }
    const float bv = W[512 * 512 + ccl];     // beff (12x already folded in)
    const int r0 = rt * 16 + wv * 4;
    float acc[4] = {a0, a1, a2, a3};
#pragma unroll
    for (int i = 0; i < 4; ++i) {
        const int row = r0 + i;
        out[(size_t)row * 1536 + l * 512 + ccl] =
            acc[i] + (counts[row] > 0 ? bv : 0.f);
    }
}

// ---------------------------------------------------------------------------
// Fallback epilogue (small-workspace path), unchanged from previous version.
// ---------------------------------------------------------------------------
__global__ __launch_bounds__(256)
void layer_gemm_kernel(const float* __restrict__ A, int lda, int scaleA,
                       const float* __restrict__ W,
                       const float* __restrict__ bias,
                       const int* __restrict__ counts,
                       float* __restrict__ out) {
    __shared__ float Alds[16][128];
    const int ct = blockIdx.x, rt = blockIdx.y, ksb = blockIdx.z;
    const int t = threadIdx.x;
    const int cc = ct * 64 + (t & 63);
    const int wv = t >> 6;
    const int k0 = ksb * 128;

    for (int idx = t; idx < 16 * 32; idx += 256) {
        const int rr = idx >> 5;
        const int kk = (idx & 31) * 4;
        const int row = rt * 16 + rr;
        float4 v = *(const float4*)&A[(size_t)row * lda + k0 + kk];
        if (scaleA) {
            const float inv = 1.f / (float)max(counts[row], 1);
            v.x *= inv; v.y *= inv; v.z *= inv; v.w *= inv;
        }
        *(float4*)&Alds[rr][kk] = v;
    }
    __syncthreads();

    const int r0 = rt * 16 + wv * 4;
    float a0 = 0.f, a1 = 0.f, a2 = 0.f, a3 = 0.f;
#pragma unroll 8
    for (int k = 0; k < 128; ++k) {
        const float wval = W[(size_t)(k0 + k) * HID + cc];
        a0 += Alds[wv * 4 + 0][k] * wval;
        a1 += Alds[wv * 4 + 1][k] * wval;
        a2 += Alds[wv * 4 + 2][k] * wval;
        a3 += Alds[wv * 4 + 3][k] * wval;
    }
    if (ksb == 0) {
        const float bc = bias[cc];
        a0 += (counts[r0 + 0] > 0 ? 12.f : 0.f) * bc;
        a1 += (counts[r0 + 1] > 0 ? 12.f : 0.f) * bc;
        a2 += (counts[r0 + 2] > 0 ? 12.f : 0.f) * bc;
        a3 += (counts[r0 + 3] > 0 ? 12.f : 0.f) * bc;
    }
    atomicAdd(&out[(size_t)(r0 + 0) * 1536 + cc], a0);
    atomicAdd(&out[(size_t)(r0 + 1) * 1536 + cc], a1);
    atomicAdd(&out[(size_t)(r0 + 2) * 1536 + cc], a2);
    atomicAdd(&out[(size_t)(r0 + 3) * 1536 + cc], a3);
}

extern "C" void kernel_launch(void* const* d_in, const int* in_sizes, int n_in,
                              void* d_out, int out_size, void* d_ws, size_t ws_size,
                              hipStream_t stream) {
    const float* x     = (const float*)d_in[0];
    const int*   w2    = (const int*)d_in[1];
    const int*   w3    = (const int*)d_in[2];
    const int*   w4    = (const int*)d_in[3];
    const int*   batch = (const int*)d_in[4];
    const float* W0    = (const float*)d_in[5];
    const float* b0    = (const float*)d_in[6];
    const float* W1    = (const float*)d_in[7];
    const float* b1    = (const float*)d_in[8];
    const float* W2    = (const float*)d_in[9];
    const float* b2    = (const float*)d_in[10];
    float* out = (float*)d_out;

    unsigned char* ws  = (unsigned char*)d_ws;
    unsigned int* C32  = (unsigned int*)(ws + C8_OFF);
    float* Psum        = (float*)(ws + PSUM_OFF);
    int* counts        = (int*)(ws + COUNTS_OFF);
    uint4* Apack       = (uint4*)(ws + APACK_OFF);
    float* part        = (float*)(ws + PART_OFF);
    float* Waug        = (float*)(ws + WAUG_OFF);
    const bool use_part = ws_size >= PART_OFF + PART_BYTES;
    const bool use_waug = ws_size >= WAUG_OFF + WAUG_BYTES;

    hipMemsetAsync(d_ws, 0, ZERO_BYTES, stream);      // C8 + Psum + counts
    if (!use_waug)
        hipMemsetAsync(d_out, 0, (size_t)out_size * 4, stream);

    build_c_kernel<<<(N_NODES + 255) / 256, 256, 0, stream>>>(w2, w3, w4, batch, C32, counts);
    c8_to_apack_kernel<<<NPANEL, 256, 0, stream>>>((const unsigned char*)C32, Apack);

    if (use_part) {
        pool_gemm5_kernel<0><<<dim3(16, KS2), 256, 0, stream>>>(x, Apack, part);
    } else {
        pool_gemm5_kernel<1><<<dim3(16, KS2), 256, 0, stream>>>(x, Apack, Psum);
    }

    if (use_waug) {
        // weight-chain precompute (independent of the data path)
        waug_init_kernel<<<(513 * 512 + 255) / 256, 256, 0, stream>>>(W0, b0, Waug);
        wchain_kernel<<<dim3(8, 33), 256, 0, stream>>>(Waug, W1, b1, Waug + 513 * 512);
        wchain_kernel<<<dim3(8, 33), 256, 0, stream>>>(Waug + 513 * 512, W2, b2,
                                                       Waug + 2 * 513 * 512);
    }

    if (use_part)
        reduce_part_kernel<<<256, 256, 0, stream>>>(part, Psum);

    if (use_waug) {
        fused_layers_kernel<<<dim3(24, 8), 256, 0, stream>>>(Psum, Waug, counts, out);
    } else {
        layer_gemm_kernel<<<dim3(8, 8, 4), 256, 0, stream>>>(Psum, HID, 1, W0, b0, counts, out);
        layer_gemm_kernel<<<dim3(8, 8, 4), 256, 0, stream>>>(out, 1536, 0, W1, b1, counts, out + 512);
        layer_gemm_kernel<<<dim3(8, 8, 4), 256, 0, stream>>>(out + 512, 1536, 0, W2, b2, counts, out + 1024);
    }
}